// Round 2
// baseline (179.318 us; speedup 1.0000x reference)
//
#include <hip/hip_runtime.h>

namespace {
constexpr int H = 512;
constexpr int W = 512;
constexpr int NC = 96;               // 32 images * 3 channels (independent planes)
constexpr int RSTRIP = 32;           // output rows per wave
constexpr int SPP = H / RSTRIP;      // 16 strips per plane
constexpr int NSTRIPS = NC * SPP;    // 1536 waves total
constexpr int WPB = 2;               // waves per block
constexpr int NTHR = WPB * 64;       // 128
constexpr int NBLK = NSTRIPS / WPB;  // 768 blocks = exactly 3 per CU
constexpr float INV_K2 = 1.0f / 49.0f;
constexpr float INV_TOTAL = 1.0f / (32.0f * 3.0f * 512.0f * 512.0f);
}

// One wave per 32-row strip, full 512-col width. Lane owns 8 columns.
// No LDS, no barriers: halo via shfl, rings fully unrolled (static indices).
__global__ __launch_bounds__(NTHR, 2) void lcl_partial(
    const float4* __restrict__ pred4, const float4* __restrict__ targ4,
    float* __restrict__ partials)
{
    const int tid   = threadIdx.x;
    const int lane  = tid & 63;
    const int wv    = tid >> 6;
    const int strip = blockIdx.x * WPB + wv;
    const int plane = strip >> 4;                 // / SPP
    const int y0    = (strip & (SPP - 1)) * RSTRIP;
    const int base4 = plane * (H * (W / 4));      // float4 index of plane start
    const int col4  = lane * 2;                   // 2 float4 = 8 cols per lane

    float hring[8][8];   // hring[i&7][c] = horizontal 7-sum of row i
    float dring[4][8];   // dring[i&3][c] = d of row i
    float vs[8];         // running vertical sum of last 7 h-rows
#pragma unroll
    for (int s = 0; s < 8; ++s) {
#pragma unroll
        for (int c = 0; c < 8; ++c) hring[s][c] = 0.f;
    }
#pragma unroll
    for (int s = 0; s < 4; ++s) {
#pragma unroll
        for (int c = 0; c < 8; ++c) dring[s][c] = 0.f;
    }
#pragma unroll
    for (int c = 0; c < 8; ++c) vs[c] = 0.f;

    float acc = 0.f;

#pragma unroll
    for (int i = 0; i < RSTRIP + 6; ++i) {        // 38 iterations, fully unrolled
        const int y = y0 - 3 + i;
        float4 d0 = make_float4(0.f, 0.f, 0.f, 0.f);
        float4 d1 = d0;
        if ((unsigned)y < (unsigned)H) {
            const int idx = base4 + y * (W / 4) + col4;
            const float4 a0 = pred4[idx];
            const float4 a1 = pred4[idx + 1];
            const float4 b0 = targ4[idx];
            const float4 b1 = targ4[idx + 1];
            d0 = make_float4(a0.x - b0.x, a0.y - b0.y, a0.z - b0.z, a0.w - b0.w);
            d1 = make_float4(a1.x - b1.x, a1.y - b1.y, a1.z - b1.z, a1.w - b1.w);
        }

        // halo from neighbor lanes (cols c0-3..c0-1 and c0+8..c0+10)
        float e0 = __shfl_up(d1.y, 1);
        float e1 = __shfl_up(d1.z, 1);
        float e2 = __shfl_up(d1.w, 1);
        if (lane == 0) { e0 = 0.f; e1 = 0.f; e2 = 0.f; }
        float r0 = __shfl_down(d0.x, 1);
        float r1 = __shfl_down(d0.y, 1);
        float r2 = __shfl_down(d0.z, 1);
        if (lane == 63) { r0 = 0.f; r1 = 0.f; r2 = 0.f; }

        const float V[14] = {e0, e1, e2, d0.x, d0.y, d0.z, d0.w,
                             d1.x, d1.y, d1.z, d1.w, r0, r1, r2};
        float h[8];
        h[0] = ((V[0] + V[1]) + (V[2] + V[3])) + ((V[4] + V[5]) + V[6]);
#pragma unroll
        for (int c = 1; c < 8; ++c) h[c] = h[c - 1] - V[c - 1] + V[c + 6];

        const int s8  = i & 7;
        const int s8o = (i + 1) & 7;   // holds h from 7 rows ago
        const int s4  = i & 3;
        const int s4o = (i + 1) & 3;   // holds d from 3 rows ago

#pragma unroll
        for (int c = 0; c < 8; ++c) {
            vs[c] += h[c] - hring[s8o][c];   // vs now covers rows i-6..i
            hring[s8][c] = h[c];
        }

        if (i >= 6) {                         // output row y0 + (i-6)
#pragma unroll
            for (int c = 0; c < 8; ++c)
                acc += fabsf(dring[s4o][c] - vs[c] * INV_K2);
        }

        dring[s4][0] = d0.x; dring[s4][1] = d0.y;
        dring[s4][2] = d0.z; dring[s4][3] = d0.w;
        dring[s4][4] = d1.x; dring[s4][5] = d1.y;
        dring[s4][6] = d1.z; dring[s4][7] = d1.w;
    }

    // wave reduce (64 lanes), one partial per wave-strip
#pragma unroll
    for (int off = 32; off > 0; off >>= 1)
        acc += __shfl_down(acc, off, 64);
    if (lane == 0) partials[strip] = acc;
}

__global__ __launch_bounds__(256) void lcl_reduce(const float* __restrict__ partials,
                                                  float* __restrict__ out)
{
    __shared__ float wred[4];
    const int tid = threadIdx.x;
    float s = 0.0f;
    for (int i = tid; i < NSTRIPS; i += 256) s += partials[i];
#pragma unroll
    for (int off = 32; off > 0; off >>= 1)
        s += __shfl_down(s, off, 64);
    if ((tid & 63) == 0) wred[tid >> 6] = s;
    __syncthreads();
    if (tid == 0) out[0] = ((wred[0] + wred[1]) + (wred[2] + wred[3])) * INV_TOTAL;
}

extern "C" void kernel_launch(void* const* d_in, const int* in_sizes, int n_in,
                              void* d_out, int out_size, void* d_ws, size_t ws_size,
                              hipStream_t stream) {
    const float4* pred4 = (const float4*)d_in[0];
    const float4* targ4 = (const float4*)d_in[1];
    float* out      = (float*)d_out;
    float* partials = (float*)d_ws;   // NSTRIPS floats = 6 KB

    lcl_partial<<<NBLK, NTHR, 0, stream>>>(pred4, targ4, partials);
    lcl_reduce<<<1, 256, 0, stream>>>(partials, out);
}

// Round 3
// 46.687 us; speedup vs baseline: 3.8408x; 3.8408x over previous
//
#include <hip/hip_runtime.h>

namespace {
constexpr int H = 512;
constexpr int W = 512;
constexpr int NC = 96;                 // 32 images * 3 channels (independent planes)
constexpr int RSTRIP = 32;             // output rows per wave
constexpr int SPP = H / RSTRIP;        // 16 row-strips per plane
constexpr int NHALF = 2;               // two 256-col halves per row
constexpr int NSTRIPS = NC * NHALF * SPP;  // 3072 waves
constexpr int WPB = 4;                 // waves per block
constexpr int NTHR = WPB * 64;         // 256
constexpr int NBLK = NSTRIPS / WPB;    // 768 = 3 blocks/CU exactly
constexpr float INV_K2 = 1.0f / 49.0f;
constexpr float INV_TOTAL = 1.0f / (32.0f * 3.0f * 512.0f * 512.0f);
}

// One row step. P8/P4 are compile-time ring phases -> all array indices static.
template <int P8, int P4, bool EMIT>
__device__ __forceinline__ void proc_row(
    const float4* __restrict__ pred4, const float4* __restrict__ targ4,
    int y, int base4, int col4, int lane, bool edgeL, bool edgeR,
    float (&hr)[8][4], float (&dr)[4][4], float (&vs)[4], float& acc)
{
    float4 d  = make_float4(0.f, 0.f, 0.f, 0.f);
    float4 dx = make_float4(0.f, 0.f, 0.f, 0.f);
    if ((unsigned)y < (unsigned)H) {
        const int idx = base4 + y * (W / 4) + col4;
        const float4 a = pred4[idx];
        const float4 b = targ4[idx];
        d.x = a.x - b.x; d.y = a.y - b.y; d.z = a.z - b.z; d.w = a.w - b.w;
        if (edgeL | edgeR) {                       // 2 lanes of 64, wave-edge halo
            const int e = idx + (edgeR ? 1 : -1);
            const float4 ea = pred4[e];
            const float4 eb = targ4[e];
            dx.x = ea.x - eb.x; dx.y = ea.y - eb.y;
            dx.z = ea.z - eb.z; dx.w = ea.w - eb.w;
        }
    }

    // column halo from neighbor lanes (4 cols/lane)
    float l1 = __shfl_up(d.y, 1);
    float l2 = __shfl_up(d.z, 1);
    float l3 = __shfl_up(d.w, 1);
    float r1 = __shfl_down(d.x, 1);
    float r2 = __shfl_down(d.y, 1);
    float r3 = __shfl_down(d.z, 1);
    if (lane == 0)  { l1 = dx.y; l2 = dx.z; l3 = dx.w; }
    if (lane == 63) { r1 = dx.x; r2 = dx.y; r3 = dx.z; }

    // horizontal 7-sums, incremental
    const float h0 = ((l1 + l2) + (l3 + d.x)) + ((d.y + d.z) + d.w);
    const float h1 = h0 - l1 + r1;
    const float h2 = h1 - l2 + r2;
    const float h3 = h2 - l3 + r3;

    constexpr int S  = P8 & 7;
    constexpr int So = (P8 + 1) & 7;   // h from 7 rows ago
    constexpr int Q  = P4 & 3;
    constexpr int Qo = (P4 + 1) & 3;   // d from 3 rows ago

    vs[0] += h0 - hr[So][0]; hr[S][0] = h0;
    vs[1] += h1 - hr[So][1]; hr[S][1] = h1;
    vs[2] += h2 - hr[So][2]; hr[S][2] = h2;
    vs[3] += h3 - hr[So][3]; hr[S][3] = h3;

    if (EMIT) {
        acc += fabsf(dr[Qo][0] - vs[0] * INV_K2)
             + fabsf(dr[Qo][1] - vs[1] * INV_K2)
             + fabsf(dr[Qo][2] - vs[2] * INV_K2)
             + fabsf(dr[Qo][3] - vs[3] * INV_K2);
    }

    dr[Q][0] = d.x; dr[Q][1] = d.y; dr[Q][2] = d.z; dr[Q][3] = d.w;
}

__global__ __launch_bounds__(NTHR, 3) void lcl_partial(
    const float4* __restrict__ pred4, const float4* __restrict__ targ4,
    float* __restrict__ partials)
{
    const int tid   = threadIdx.x;
    const int lane  = tid & 63;
    const int wv    = tid >> 6;
    const int strip = blockIdx.x * WPB + wv;
    const int plane = strip >> 5;                    // / 32
    const int rem   = strip & 31;
    const int half  = rem >> 4;
    const int y0    = (rem & 15) * RSTRIP;
    const int base4 = plane * (H * (W / 4));
    const int col4  = half * 64 + lane;              // float4 index in row (0..127)
    const bool edgeL = (lane == 0)  && (half == 1);
    const bool edgeR = (lane == 63) && (half == 0);

    float hr[8][4], dr[4][4], vs[4];
#pragma unroll
    for (int s = 0; s < 8; ++s) { hr[s][0]=0.f; hr[s][1]=0.f; hr[s][2]=0.f; hr[s][3]=0.f; }
#pragma unroll
    for (int s = 0; s < 4; ++s) { dr[s][0]=0.f; dr[s][1]=0.f; dr[s][2]=0.f; dr[s][3]=0.f; }
    vs[0]=0.f; vs[1]=0.f; vs[2]=0.f; vs[3]=0.f;
    float acc = 0.f;

    // prologue: rows y0-3 .. y0+2 (phases I=0..5), no output yet
    proc_row<0, 0, false>(pred4, targ4, y0 - 3, base4, col4, lane, edgeL, edgeR, hr, dr, vs, acc);
    proc_row<1, 1, false>(pred4, targ4, y0 - 2, base4, col4, lane, edgeL, edgeR, hr, dr, vs, acc);
    proc_row<2, 2, false>(pred4, targ4, y0 - 1, base4, col4, lane, edgeL, edgeR, hr, dr, vs, acc);
    proc_row<3, 3, false>(pred4, targ4, y0    , base4, col4, lane, edgeL, edgeR, hr, dr, vs, acc);
    proc_row<4, 0, false>(pred4, targ4, y0 + 1, base4, col4, lane, edgeL, edgeR, hr, dr, vs, acc);
    proc_row<5, 1, false>(pred4, targ4, y0 + 2, base4, col4, lane, edgeL, edgeR, hr, dr, vs, acc);

    // steady state: 4 runtime iterations x 8-row unrolled body (phases repeat mod 8)
#pragma unroll 1
    for (int b = 0; b < 4; ++b) {
        const int yb = y0 + 3 + b * 8;
        proc_row<6, 2, true>(pred4, targ4, yb    , base4, col4, lane, edgeL, edgeR, hr, dr, vs, acc);
        proc_row<7, 3, true>(pred4, targ4, yb + 1, base4, col4, lane, edgeL, edgeR, hr, dr, vs, acc);
        proc_row<0, 0, true>(pred4, targ4, yb + 2, base4, col4, lane, edgeL, edgeR, hr, dr, vs, acc);
        proc_row<1, 1, true>(pred4, targ4, yb + 3, base4, col4, lane, edgeL, edgeR, hr, dr, vs, acc);
        proc_row<2, 2, true>(pred4, targ4, yb + 4, base4, col4, lane, edgeL, edgeR, hr, dr, vs, acc);
        proc_row<3, 3, true>(pred4, targ4, yb + 5, base4, col4, lane, edgeL, edgeR, hr, dr, vs, acc);
        proc_row<4, 0, true>(pred4, targ4, yb + 6, base4, col4, lane, edgeL, edgeR, hr, dr, vs, acc);
        proc_row<5, 1, true>(pred4, targ4, yb + 7, base4, col4, lane, edgeL, edgeR, hr, dr, vs, acc);
    }

    // wave reduce, one partial per strip
#pragma unroll
    for (int off = 32; off > 0; off >>= 1)
        acc += __shfl_down(acc, off, 64);
    if (lane == 0) partials[strip] = acc;
}

__global__ __launch_bounds__(256) void lcl_reduce(const float* __restrict__ partials,
                                                  float* __restrict__ out)
{
    __shared__ float wred[4];
    const int tid = threadIdx.x;
    float s = 0.0f;
    for (int i = tid; i < NSTRIPS; i += 256) s += partials[i];
#pragma unroll
    for (int off = 32; off > 0; off >>= 1)
        s += __shfl_down(s, off, 64);
    if ((tid & 63) == 0) wred[tid >> 6] = s;
    __syncthreads();
    if (tid == 0) out[0] = ((wred[0] + wred[1]) + (wred[2] + wred[3])) * INV_TOTAL;
}

extern "C" void kernel_launch(void* const* d_in, const int* in_sizes, int n_in,
                              void* d_out, int out_size, void* d_ws, size_t ws_size,
                              hipStream_t stream) {
    const float4* pred4 = (const float4*)d_in[0];
    const float4* targ4 = (const float4*)d_in[1];
    float* out      = (float*)d_out;
    float* partials = (float*)d_ws;   // NSTRIPS floats = 12 KB

    lcl_partial<<<NBLK, NTHR, 0, stream>>>(pred4, targ4, partials);
    lcl_reduce<<<1, 256, 0, stream>>>(partials, out);
}